// Round 6
// baseline (60.905 us; speedup 1.0000x reference)
//
#include <hip/hip_runtime.h>

#define CHUNK 8
#define NCHUNK 64
#define TDIM 512
#define HW 9216            // 96*96
#define NT 768             // 12 waves
#define NWAVE 12
#define F4C 2304           // float4 slots per channel (9216/4)
#define NSLOT (8*F4C)      // 18432 f4 slots per chunk (contiguous in memory)
#define CITERS (NSLOT/NT)  // 24 copy iterations
#define GITERS (F4C/NT)    // 3 gram/pass2 iterations

typedef float floatx4 __attribute__((ext_vector_type(4)));

__host__ __device__ constexpr int PairIdx(int c, int j) {   // c<j strict, 28 entries
    return 7*c - (c*(c-1))/2 + (j - c - 1);
}

__device__ __forceinline__ unsigned bf16_rne(float f) {
    unsigned u = __float_as_uint(f);
    return (u + 0x7fffu + ((u >> 16) & 1u)) >> 16;   // round-to-nearest-even
}

// Pass 1 is a pure linear streaming copy (chunk = 288KB contiguous), packing
// bf16 into LDS; diag-Gram + rowsums computed in fp32 during the copy
// (channel = it/3 is compile-time). Off-diag Gram read back from LDS.
// Tests H1: 1-stream copy streams at memcpy rate where 8-stream didn't.
__global__ __launch_bounds__(NT)
void lcsap_kernel(const float* __restrict__ x,
                  const float* __restrict__ Wq, const float* __restrict__ bq,
                  const float* __restrict__ Wk, const float* __restrict__ bk,
                  const float* __restrict__ Wv, const float* __restrict__ bv,
                  float* __restrict__ out)
{
    const int bid = blockIdx.x;
    const int b   = bid >> 6;   // batch
    const int n   = bid & 63;   // chunk
    const int tid = threadIdx.x;
    const int lane = tid & 63;
    const int wid  = tid >> 6;

    const float* xb = x + ((size_t)(b*TDIM + n*CHUNK)) * HW;
    float* ob = out + ((size_t)(b*NCHUNK + n)) * HW;
    const floatx4* xf4 = reinterpret_cast<const floatx4*>(xb);

    __shared__ uint2 xs[NSLOT];          // 147456 B, linear: slot s = c*F4C + f
    __shared__ float red[NWAVE][44];
    __shared__ float Gf[64];             // full symmetric Gram
    __shared__ float sf[8];              // row sums
    __shared__ float Mld[64];            // M = attn * Wv
    __shared__ float tld[8];             // t = attn * bv

    // ---------- phase A: linear streaming copy + fp32 diag/rowsum ----------
    float accs[8], accd[8];
    #pragma unroll
    for (int c = 0; c < 8; ++c) { accs[c] = 0.f; accd[c] = 0.f; }

    floatx4 buf[2][4];
    #pragma unroll
    for (int k = 0; k < 4; ++k)
        buf[0][k] = xf4[k*NT + tid];

    #pragma unroll
    for (int obt = 0; obt < 6; ++obt) {
        const int pb = obt & 1, nb = pb ^ 1;
        if (obt < 5) {
            #pragma unroll
            for (int k = 0; k < 4; ++k)
                buf[nb][k] = xf4[(obt*4 + 4 + k)*NT + tid];
        }
        #pragma unroll
        for (int k = 0; k < 4; ++k) {
            const int it = obt*4 + k;      // 0..23
            const int c  = it / 3;         // compile-time channel
            const int s  = it*NT + tid;
            floatx4 v = buf[pb][k];
            #pragma unroll
            for (int u = 0; u < 4; ++u) {
                accs[c] += v[u];
                accd[c] += v[u]*v[u];
            }
            uint2 p;
            p.x = bf16_rne(v[0]) | (bf16_rne(v[1]) << 16);
            p.y = bf16_rne(v[2]) | (bf16_rne(v[3]) << 16);
            xs[s] = p;
        }
    }
    __syncthreads();

    // ---------- phase B: off-diag Gram from LDS (bf16) ----------
    float g[28];
    #pragma unroll
    for (int i = 0; i < 28; ++i) g[i] = 0.f;

    #pragma unroll
    for (int it = 0; it < GITERS; ++it) {
        const int f = it*NT + tid;
        float xv[8][4];
        #pragma unroll
        for (int c = 0; c < 8; ++c) {
            uint2 w = xs[c*F4C + f];
            xv[c][0] = __uint_as_float(w.x << 16);
            xv[c][1] = __uint_as_float(w.x & 0xffff0000u);
            xv[c][2] = __uint_as_float(w.y << 16);
            xv[c][3] = __uint_as_float(w.y & 0xffff0000u);
        }
        #pragma unroll
        for (int u = 0; u < 4; ++u) {
            #pragma unroll
            for (int c = 0; c < 8; ++c) {
                #pragma unroll
                for (int j = c+1; j < 8; ++j)
                    g[PairIdx(c,j)] += xv[c][u]*xv[j][u];
            }
        }
    }

    // wave butterfly reduce of 28 offdiag + 8 diag + 8 rowsum
    #pragma unroll
    for (int i = 0; i < 28; ++i) {
        g[i] += __shfl_xor(g[i], 1);  g[i] += __shfl_xor(g[i], 2);
        g[i] += __shfl_xor(g[i], 4);  g[i] += __shfl_xor(g[i], 8);
        g[i] += __shfl_xor(g[i], 16); g[i] += __shfl_xor(g[i], 32);
    }
    #pragma unroll
    for (int c = 0; c < 8; ++c) {
        accd[c] += __shfl_xor(accd[c], 1);  accd[c] += __shfl_xor(accd[c], 2);
        accd[c] += __shfl_xor(accd[c], 4);  accd[c] += __shfl_xor(accd[c], 8);
        accd[c] += __shfl_xor(accd[c], 16); accd[c] += __shfl_xor(accd[c], 32);
        accs[c] += __shfl_xor(accs[c], 1);  accs[c] += __shfl_xor(accs[c], 2);
        accs[c] += __shfl_xor(accs[c], 4);  accs[c] += __shfl_xor(accs[c], 8);
        accs[c] += __shfl_xor(accs[c], 16); accs[c] += __shfl_xor(accs[c], 32);
    }
    if (lane == 0) {
        #pragma unroll
        for (int i = 0; i < 28; ++i) red[wid][i] = g[i];
        #pragma unroll
        for (int c = 0; c < 8; ++c) { red[wid][28+c] = accd[c]; red[wid][36+c] = accs[c]; }
    }
    __syncthreads();
    if (tid < 44) {
        float v = 0.f;
        #pragma unroll
        for (int w = 0; w < NWAVE; ++w) v += red[w][tid];
        if (tid < 28) {
            int c = 0, base = 0;
            for (; c < 8; ++c) { int w = 7 - c; if (tid < base + w) break; base += w; }
            int j = c + 1 + (tid - base);
            Gf[c*8+j] = v;
            Gf[j*8+c] = v;
        } else if (tid < 36) {
            Gf[(tid-28)*9] = v;
        } else {
            sf[tid-36] = v;
        }
    }
    __syncthreads();

    // ---------- phase C: tiny 8x8 attention on wave 0 ----------
    if (tid < 64) {
        const int qi = tid >> 3;
        const int ki = tid & 7;
        float wq[8], wk[8];
        #pragma unroll
        for (int c = 0; c < 8; ++c) {
            wq[c] = Wq[n*64 + qi*8 + c];
            wk[c] = Wk[n*64 + ki*8 + c];
        }
        float sc = 0.f, qs = 0.f, ks_ = 0.f;
        #pragma unroll
        for (int c = 0; c < 8; ++c) {
            float tmp = 0.f;
            #pragma unroll
            for (int d = 0; d < 8; ++d) tmp += Gf[c*8+d]*wk[d];
            sc += wq[c]*tmp;
            qs += wq[c]*sf[c];
            ks_ += wk[c]*sf[c];
        }
        const float bqv = bq[n*8+qi];
        const float bkv = bk[n*8+ki];
        sc += qs*bkv + bqv*ks_ + (float)HW * bqv * bkv;
        sc *= (1.0f/96.0f);   // 1/sqrt(9216)

        float m = sc;
        m = fmaxf(m, __shfl_xor(m, 1, 8));
        m = fmaxf(m, __shfl_xor(m, 2, 8));
        m = fmaxf(m, __shfl_xor(m, 4, 8));
        float e = expf(sc - m);
        float se = e;
        se += __shfl_xor(se, 1, 8);
        se += __shfl_xor(se, 2, 8);
        se += __shfl_xor(se, 4, 8);
        const float attn = e / se;

        float mv = 0.f;
        #pragma unroll
        for (int k = 0; k < 8; ++k) {
            float ak = __shfl(attn, k, 8);
            mv += ak * Wv[n*64 + k*8 + ki];
        }
        Mld[qi*8 + ki] = mv;

        float tv = attn * bv[n*8 + ki];
        tv += __shfl_xor(tv, 1, 8);
        tv += __shfl_xor(tv, 2, 8);
        tv += __shfl_xor(tv, 4, 8);
        if (ki == 0) tld[qi] = tv;
    }
    __syncthreads();

    // ---------- phase D: pooled = x^T M x + t^T x, from LDS ----------
    float diag[8], tt[8], su[28];
    #pragma unroll
    for (int c = 0; c < 8; ++c) { diag[c] = Mld[c*9]; tt[c] = tld[c]; }
    #pragma unroll
    for (int c = 0; c < 8; ++c) {
        #pragma unroll
        for (int j = c+1; j < 8; ++j)
            su[PairIdx(c,j)] = Mld[c*8+j] + Mld[j*8+c];
    }

    #pragma unroll
    for (int it = 0; it < GITERS; ++it) {
        const int f = it*NT + tid;
        float xv[8][4];
        #pragma unroll
        for (int c = 0; c < 8; ++c) {
            uint2 w = xs[c*F4C + f];
            xv[c][0] = __uint_as_float(w.x << 16);
            xv[c][1] = __uint_as_float(w.x & 0xffff0000u);
            xv[c][2] = __uint_as_float(w.y << 16);
            xv[c][3] = __uint_as_float(w.y & 0xffff0000u);
        }
        floatx4 o;
        #pragma unroll
        for (int u = 0; u < 4; ++u) {
            float acc = 0.f;
            #pragma unroll
            for (int c = 0; c < 8; ++c) acc += tt[c]*xv[c][u];
            #pragma unroll
            for (int c = 0; c < 8; ++c) acc += diag[c]*xv[c][u]*xv[c][u];
            #pragma unroll
            for (int c = 0; c < 8; ++c) {
                #pragma unroll
                for (int j = c+1; j < 8; ++j)
                    acc += su[PairIdx(c,j)]*xv[c][u]*xv[j][u];
            }
            o[u] = acc;
        }
        reinterpret_cast<floatx4*>(ob)[f] = o;
    }
}

extern "C" void kernel_launch(void* const* d_in, const int* in_sizes, int n_in,
                              void* d_out, int out_size, void* d_ws, size_t ws_size,
                              hipStream_t stream) {
    const float* x  = (const float*)d_in[0];
    const float* Wq = (const float*)d_in[1];
    const float* bq = (const float*)d_in[2];
    const float* Wk = (const float*)d_in[3];
    const float* bk = (const float*)d_in[4];
    const float* Wv = (const float*)d_in[5];
    const float* bv = (const float*)d_in[6];
    float* out = (float*)d_out;

    lcsap_kernel<<<dim3(512), dim3(NT), 0, stream>>>(x, Wq, bq, Wk, bk, Wv, bv, out);
}